// Round 4
// baseline (166.918 us; speedup 1.0000x reference)
//
#include <hip/hip_runtime.h>

// Bidirectional NN (Chamfer-style) L1 loss on 2-D points.
//   preds: (B=64, N=2048, F=4) fp32, targs: (B=64, M=2048, F=4) fp32,
//   subcoef: (D=2,) fp32.
//
// Key ideas this version:
//  * argmin via packed key: key = (bits(d2) & ~0x7FF) | m, reduced with
//    unsigned min (v_min3_u32). d2 = |t|^2 - 2p.t + |p|^2 >= 0 so float bits
//    are unsigned-monotone; low 11 mantissa bits hold the candidate index
//    (M=2048). Exact ties pick the smaller m = first occurrence (jnp.argmin).
//  * candidates prepped into d_ws as X/Y/NRM arrays -> wave-uniform loads
//    (s_load through scalar cache), no LDS and no VMEM in the hot loop.
//  * packed <2 x float> math (v_pk_add / v_pk_fma).
constexpr int B = 64;
constexpr int N = 2048;
constexpr int M = 2048;
constexpr int F = 4;
constexpr int BLOCK = 256;

typedef float v2f __attribute__((ext_vector_type(2)));
typedef float v8f __attribute__((ext_vector_type(8)));

constexpr size_t PTS = (size_t)2 * B * M;              // points per "side" table
constexpr size_t WS_NEEDED = PTS * 3 * sizeof(float);  // X, Y, NRM

__device__ __forceinline__ unsigned fbits(float x) {
    union { float f; unsigned u; } c; c.f = x; return c.u;
}

// side 0 = targs (candidates for dir 0), side 1 = preds (candidates for dir 1).
__global__ void __launch_bounds__(BLOCK)
prep_kernel(const float* __restrict__ preds,
            const float* __restrict__ targs,
            float* __restrict__ X, float* __restrict__ Y,
            float* __restrict__ NRM) {
    const size_t g = (size_t)blockIdx.x * BLOCK + threadIdx.x;   // 0 .. 2*B*M
    const size_t half = (size_t)B * M;
    const float* src = (g < half) ? targs : preds;
    const size_t r = (g < half) ? g : g - half;                  // b*M + m
    const float2 c = *reinterpret_cast<const float2*>(src + r * F);
    X[g] = c.x;
    Y[g] = c.y;
    NRM[g] = fmaf(c.y, c.y, c.x * c.x);
}

// ---------- main kernel, scalar-cache candidate path (P=1) ----------
__global__ void __launch_bounds__(BLOCK)
nn_main(const float* __restrict__ preds,
        const float* __restrict__ targs,
        const float* __restrict__ subcoef,
        const float* __restrict__ X, const float* __restrict__ Y,
        const float* __restrict__ NRM,
        float* __restrict__ out) {
    __shared__ float wsum[BLOCK / 64];

    const int dir = blockIdx.z;     // 0: preds->targs (subcoef), 1: reverse
    const int b   = blockIdx.y;
    const int tid = threadIdx.x;

    const float* src = dir ? targs : preds;
    const size_t cb = ((size_t)dir * B + b) * M;   // candidate table offset
    const float* Xb = X + cb;
    const float* Yb = Y + cb;
    const float* Nb = NRM + cb;

    const int n = blockIdx.x * BLOCK + tid;
    const float2 p = *reinterpret_cast<const float2*>(src + ((size_t)b * N + n) * F);
    const float p2 = fmaf(p.y, p.y, p.x * p.x);
    const v2f n2x = { -2.0f * p.x, -2.0f * p.x };
    const v2f n2y = { -2.0f * p.y, -2.0f * p.y };
    const v2f p2v = { p2, p2 };

    unsigned bkey = 0xFFFFFFFFu;
    // 8 candidates per chunk: 3 uniform 32B loads (s_load_dwordx8 expected).
    #pragma unroll 2
    for (int c = 0; c < M / 8; ++c) {
        const v8f cx = *reinterpret_cast<const v8f*>(Xb + 8 * c);
        const v8f cy = *reinterpret_cast<const v8f*>(Yb + 8 * c);
        const v8f cn = *reinterpret_cast<const v8f*>(Nb + 8 * c);
        const int mbase = 8 * c;
        #pragma unroll
        for (int q = 0; q < 4; ++q) {
            const v2f XX = { cx[2 * q], cx[2 * q + 1] };
            const v2f YY = { cy[2 * q], cy[2 * q + 1] };
            const v2f NN = { cn[2 * q], cn[2 * q + 1] };
            // d2 = |t|^2 + |p|^2 - 2 p.t  (>= 0 up to rounding), 2 wide.
            const v2f base = NN + p2v;                              // v_pk_add
            v2f d = __builtin_elementwise_fma(XX, n2x, base);       // v_pk_fma
            d = __builtin_elementwise_fma(YY, n2y, d);              // v_pk_fma
            const unsigned k0 = (fbits(d.x) & 0xFFFFF800u) | (unsigned)(mbase + 2 * q);
            const unsigned k1 = (fbits(d.y) & 0xFFFFF800u) | (unsigned)(mbase + 2 * q + 1);
            const unsigned km = k0 < k1 ? k0 : k1;                  // -> v_min3_u32
            bkey = km < bkey ? km : bkey;
        }
    }

    const int m = (int)(bkey & 0x7FFu);
    const float qx = Xb[m];          // divergent gather (vector path), 2 loads
    const float qy = Yb[m];
    float c0 = 1.0f, c1 = 1.0f;
    if (dir == 0) { c0 = subcoef[0]; c1 = subcoef[1]; }
    float acc = fabsf(p.x - qx) * c0 + fabsf(p.y - qy) * c1;

    #pragma unroll
    for (int off = 32; off > 0; off >>= 1) acc += __shfl_down(acc, off, 64);
    if ((tid & 63) == 0) wsum[tid >> 6] = acc;
    __syncthreads();
    if (tid == 0) {
        float s = 0.0f;
        #pragma unroll
        for (int w = 0; w < BLOCK / 64; ++w) s += wsum[w];
        atomicAdd(out, s);
    }
}

// ---------- fallback (ws too small): LDS staging + key trick, P=2 ----------
constexpr int PF = 2;
__global__ void __launch_bounds__(BLOCK)
nn_fallback(const float* __restrict__ preds,
            const float* __restrict__ targs,
            const float* __restrict__ subcoef,
            float* __restrict__ out) {
    __shared__ float sc[M * 2];          // pair-interleaved [x0,x1,y0,y1]
    __shared__ float wsum[BLOCK / 64];

    const int dir = blockIdx.z;
    const int b   = blockIdx.y;
    const int tid = threadIdx.x;

    const float* src = dir ? targs : preds;
    const float* dst = dir ? preds : targs;

    const float* dstb = dst + (size_t)b * M * F;
    for (int i = tid; i < M; i += BLOCK) {
        const float2 c = *reinterpret_cast<const float2*>(dstb + (size_t)i * F);
        const int g = i >> 1, o = i & 1;
        sc[g * 4 + o]     = c.x;
        sc[g * 4 + 2 + o] = c.y;
    }
    __syncthreads();

    const int base = blockIdx.x * (BLOCK * PF);
    float px[PF], py[PF];
    v2f n2x[PF], n2y[PF], p2v[PF];
    unsigned bkey[PF];
    #pragma unroll
    for (int j = 0; j < PF; ++j) {
        const int n = base + j * BLOCK + tid;
        const float2 p = *reinterpret_cast<const float2*>(src + ((size_t)b * N + n) * F);
        px[j] = p.x;  py[j] = p.y;
        const float p2 = fmaf(p.y, p.y, p.x * p.x);
        n2x[j] = (v2f){ -2.0f * p.x, -2.0f * p.x };
        n2y[j] = (v2f){ -2.0f * p.y, -2.0f * p.y };
        p2v[j] = (v2f){ p2, p2 };
        bkey[j] = 0xFFFFFFFFu;
    }

    const float4* sc4 = reinterpret_cast<const float4*>(sc);
    #pragma unroll 4
    for (int mp = 0; mp < M / 2; ++mp) {
        const float4 qq = sc4[mp];
        const v2f XX = { qq.x, qq.y };
        const v2f YY = { qq.z, qq.w };
        const v2f NN = __builtin_elementwise_fma(YY, YY, XX * XX);
        #pragma unroll
        for (int j = 0; j < PF; ++j) {
            const v2f bb = NN + p2v[j];
            v2f d = __builtin_elementwise_fma(XX, n2x[j], bb);
            d = __builtin_elementwise_fma(YY, n2y[j], d);
            const unsigned k0 = (fbits(d.x) & 0xFFFFF800u) | (unsigned)(2 * mp);
            const unsigned k1 = (fbits(d.y) & 0xFFFFF800u) | (unsigned)(2 * mp + 1);
            const unsigned km = k0 < k1 ? k0 : k1;
            bkey[j] = km < bkey[j] ? km : bkey[j];
        }
    }

    float c0 = 1.0f, c1 = 1.0f;
    if (dir == 0) { c0 = subcoef[0]; c1 = subcoef[1]; }
    float acc = 0.0f;
    #pragma unroll
    for (int j = 0; j < PF; ++j) {
        const int m = (int)(bkey[j] & 0x7FFu);
        const int g = m >> 1, o = m & 1;
        acc += fabsf(px[j] - sc[g * 4 + o]) * c0 +
               fabsf(py[j] - sc[g * 4 + 2 + o]) * c1;
    }

    #pragma unroll
    for (int off = 32; off > 0; off >>= 1) acc += __shfl_down(acc, off, 64);
    if ((tid & 63) == 0) wsum[tid >> 6] = acc;
    __syncthreads();
    if (tid == 0) {
        float s = 0.0f;
        #pragma unroll
        for (int w = 0; w < BLOCK / 64; ++w) s += wsum[w];
        atomicAdd(out, s);
    }
}

extern "C" void kernel_launch(void* const* d_in, const int* in_sizes, int n_in,
                              void* d_out, int out_size, void* d_ws, size_t ws_size,
                              hipStream_t stream) {
    const float* preds   = (const float*)d_in[0];
    const float* targs   = (const float*)d_in[1];
    const float* subcoef = (const float*)d_in[2];
    float* out = (float*)d_out;

    hipMemsetAsync(out, 0, sizeof(float), stream);

    if (d_ws != nullptr && ws_size >= WS_NEEDED) {
        float* X   = (float*)d_ws;
        float* Y   = X + PTS;
        float* NRM = Y + PTS;
        prep_kernel<<<dim3((unsigned)(PTS / BLOCK)), BLOCK, 0, stream>>>(
            preds, targs, X, Y, NRM);
        dim3 grid(N / BLOCK, B, 2);                 // 1024 blocks, 4 waves/SIMD
        nn_main<<<grid, BLOCK, 0, stream>>>(preds, targs, subcoef, X, Y, NRM, out);
    } else {
        dim3 grid(N / (BLOCK * PF), B, 2);          // 512 blocks
        nn_fallback<<<grid, BLOCK, 0, stream>>>(preds, targs, subcoef, out);
    }
}

// Round 5
// 131.821 us; speedup vs baseline: 1.2662x; 1.2662x over previous
//
#include <hip/hip_runtime.h>

// Bidirectional NN (Chamfer-style) L1 loss on 2-D points.
//   preds: (B=64, N=2048, F=4) fp32, targs: (B=64, M=2048, F=4) fp32,
//   subcoef: (D=2,) fp32. Distance over features [0:2) only.
//
// Structure (winner so far: LDS-broadcast candidates, 2 waves/SIMD):
//  * d2 = |p|^2 + |t|^2 - 2 p.t  (>= 0 up to rounding), packed 2-wide
//    (v_pk_add_f32 / v_pk_fma_f32), candidates pair-interleaved in LDS.
//  * two-level argmin: per 16-candidate chunk keep only min VALUE
//    (v_min3_f32, 1 instr per pair per point); per chunk fold a packed key
//      key = (bits(d2min) & 0xFFFFF800) | chunk_id
//    with v_min_u32. Float bits of nonneg d2 are unsigned-monotone; masking
//    low 11 mantissa bits keeps ~2^-12 RELATIVE precision (fine near 0).
//    Ties -> smaller chunk_id. Tail re-scans the winning 16 candidates with
//    BIT-IDENTICAL arithmetic and takes the first masked-equal index ==
//    first-occurrence argmin (same semantics as round-4 key kernel, absmax 0).
constexpr int B = 64;
constexpr int N = 2048;
constexpr int M = 2048;
constexpr int F = 4;
constexpr int BLOCK = 256;
constexpr int P = 2;                  // points per thread -> 512 blocks, 2 waves/SIMD
constexpr int CHUNK = 16;             // candidates per chunk
constexpr int NCHUNK = M / CHUNK;     // 128 (chunk_id fits low 11 bits)
constexpr unsigned DMASK = 0xFFFFF800u;

typedef float v2f __attribute__((ext_vector_type(2)));

__device__ __forceinline__ unsigned fbits(float x) {
    union { float f; unsigned u; } c; c.f = x; return c.u;
}
__device__ __forceinline__ float min3f(float a, float b, float c) {
    float r;
    asm("v_min3_f32 %0, %1, %2, %3" : "=v"(r) : "v"(a), "v"(b), "v"(c));
    return r;
}

__global__ void __launch_bounds__(BLOCK)
nn_kernel(const float* __restrict__ preds,
          const float* __restrict__ targs,
          const float* __restrict__ subcoef,
          float* __restrict__ out) {
    __shared__ float sc[M * 2];          // pair-interleaved [x0,x1,y0,y1] per 16B
    __shared__ float wsum[BLOCK / 64];

    const int dir = blockIdx.z;          // 0: preds->targs (subcoef), 1: reverse
    const int b   = blockIdx.y;
    const int tid = threadIdx.x;

    const float* src = dir ? targs : preds;
    const float* dst = dir ? preds : targs;

    // Stage candidates: one ds_write_b128 per pair, built in registers.
    const float* dstb = dst + (size_t)b * M * F;
    float4* scw = reinterpret_cast<float4*>(sc);
    for (int g = tid; g < M / 2; g += BLOCK) {
        const float4 a = *reinterpret_cast<const float4*>(dstb + (size_t)(2 * g) * F);
        const float4 c = *reinterpret_cast<const float4*>(dstb + (size_t)(2 * g + 1) * F);
        scw[g] = make_float4(a.x, c.x, a.y, c.y);
    }
    __syncthreads();

    // Each thread owns P query points (stride BLOCK for coalescing).
    const int base = blockIdx.x * (BLOCK * P);
    float px[P], py[P], p2s[P];
    v2f n2x[P], n2y[P], p2v[P];
    unsigned bkey[P];
    #pragma unroll
    for (int j = 0; j < P; ++j) {
        const int n = base + j * BLOCK + tid;
        const float2 p = *reinterpret_cast<const float2*>(src + ((size_t)b * N + n) * F);
        px[j] = p.x;  py[j] = p.y;
        p2s[j] = fmaf(p.y, p.y, p.x * p.x);
        n2x[j] = (v2f){ -2.0f * p.x, -2.0f * p.x };
        n2y[j] = (v2f){ -2.0f * p.y, -2.0f * p.y };
        p2v[j] = (v2f){ p2s[j], p2s[j] };
        bkey[j] = 0xFFFFFFFFu;
    }

    const float4* sc4 = reinterpret_cast<const float4*>(sc);
    for (int c = 0; c < NCHUNK; ++c) {
        float cb[P];
        #pragma unroll
        for (int j = 0; j < P; ++j) cb[j] = 3.4028235e38f;
        #pragma unroll
        for (int i = 0; i < CHUNK / 2; ++i) {
            const float4 q = sc4[c * (CHUNK / 2) + i];
            const v2f XX = { q.x, q.y };
            const v2f YY = { q.z, q.w };
            const v2f NN = __builtin_elementwise_fma(YY, YY, XX * XX);
            #pragma unroll
            for (int j = 0; j < P; ++j) {
                v2f d = __builtin_elementwise_fma(XX, n2x[j], NN + p2v[j]);
                d = __builtin_elementwise_fma(YY, n2y[j], d);
                cb[j] = min3f(d.x, d.y, cb[j]);
            }
        }
        #pragma unroll
        for (int j = 0; j < P; ++j) {
            const unsigned key = (fbits(cb[j]) & DMASK) | (unsigned)c;
            bkey[j] = key < bkey[j] ? key : bkey[j];
        }
    }

    // Tail: re-scan winning chunk (bit-identical math) for first-occurrence index.
    float c0 = 1.0f, c1 = 1.0f;
    if (dir == 0) { c0 = subcoef[0]; c1 = subcoef[1]; }
    float acc = 0.0f;
    #pragma unroll
    for (int j = 0; j < P; ++j) {
        const int cwin = (int)(bkey[j] & 0x7FFu);
        const unsigned dbits = bkey[j] & DMASK;
        const float a2x = -2.0f * px[j];   // same value as n2x lanes
        const float a2y = -2.0f * py[j];
        int mwin = 0x7FFFFFFF;
        #pragma unroll
        for (int i = 0; i < CHUNK; ++i) {
            const int m = cwin * CHUNK + i;
            const int g = m >> 1, o = m & 1;
            const float qx = sc[g * 4 + o];
            const float qy = sc[g * 4 + 2 + o];
            const float nrm = fmaf(qy, qy, qx * qx);
            float d = fmaf(qx, a2x, nrm + p2s[j]);
            d = fmaf(qy, a2y, d);
            const bool hit = (fbits(d) & DMASK) == dbits;
            mwin = (hit && m < mwin) ? m : mwin;
        }
        if (mwin == 0x7FFFFFFF) mwin = cwin * CHUNK;   // unreachable safety
        const int g = mwin >> 1, o = mwin & 1;
        acc += fabsf(px[j] - sc[g * 4 + o])     * c0 +
               fabsf(py[j] - sc[g * 4 + 2 + o]) * c1;
    }

    // Wave (64) shuffle reduction -> block reduction -> one atomic per block.
    #pragma unroll
    for (int off = 32; off > 0; off >>= 1) acc += __shfl_down(acc, off, 64);
    if ((tid & 63) == 0) wsum[tid >> 6] = acc;
    __syncthreads();
    if (tid == 0) {
        float s = 0.0f;
        #pragma unroll
        for (int w = 0; w < BLOCK / 64; ++w) s += wsum[w];
        atomicAdd(out, s);
    }
}

extern "C" void kernel_launch(void* const* d_in, const int* in_sizes, int n_in,
                              void* d_out, int out_size, void* d_ws, size_t ws_size,
                              hipStream_t stream) {
    const float* preds   = (const float*)d_in[0];
    const float* targs   = (const float*)d_in[1];
    const float* subcoef = (const float*)d_in[2];
    float* out = (float*)d_out;

    hipMemsetAsync(out, 0, sizeof(float), stream);

    // 4 x 64 x 2 = 512 blocks -> 2 blocks/CU -> 8 waves/CU (2 per SIMD).
    dim3 grid(N / (BLOCK * P), B, 2);
    nn_kernel<<<grid, BLOCK, 0, stream>>>(preds, targs, subcoef, out);
}

// Round 6
// 124.664 us; speedup vs baseline: 1.3389x; 1.0574x over previous
//
#include <hip/hip_runtime.h>

// Bidirectional NN (Chamfer-style) L1 loss on 2-D points.
//   preds: (B=64, N=2048, F=4) fp32, targs: (B=64, M=2048, F=4) fp32,
//   subcoef: (D=2,) fp32. Distance over features [0:2) only.
//
// Round-6 changes vs round 5:
//  * Packed fp32 math forced via inline asm (v_pk_mul/add/fma_f32). Per-half
//    these are IEEE-identical to scalar fmaf, so the tail's scalar recompute
//    is still bit-identical to the main loop.
//  * Chunk stride padded 128B -> 144B (9 float4 slots / 16-cand chunk): the
//    divergent tail no longer maps every lane's chunk base to bank 0
//    (4*cwin mod 32 spreads over 8 bank groups). Round-5 counter showed
//    7.23M conflict cycles from exactly this.
//  * Tail re-scan uses float4 reads (8 per point instead of 32 b32).
constexpr int B = 64;
constexpr int N = 2048;
constexpr int M = 2048;
constexpr int F = 4;
constexpr int BLOCK = 256;
constexpr int P = 2;                   // points per thread
constexpr int CHUNK = 16;              // candidates per chunk
constexpr int NCHUNK = M / CHUNK;      // 128
constexpr int CH_F4 = 9;               // float4 slots per chunk (8 data + 1 pad)
constexpr unsigned DMASK = 0xFFFFF800u;

typedef float v2f __attribute__((ext_vector_type(2)));

__device__ __forceinline__ unsigned fbits(float x) {
    union { float f; unsigned u; } c; c.f = x; return c.u;
}
__device__ __forceinline__ float min3f(float a, float b, float c) {
    float r;
    asm("v_min3_f32 %0, %1, %2, %3" : "=v"(r) : "v"(a), "v"(b), "v"(c));
    return r;
}
__device__ __forceinline__ v2f pk_mul(v2f a, v2f b) {
    v2f d;
    asm("v_pk_mul_f32 %0, %1, %2" : "=v"(d) : "v"(a), "v"(b));
    return d;
}
__device__ __forceinline__ v2f pk_add(v2f a, v2f b) {
    v2f d;
    asm("v_pk_add_f32 %0, %1, %2" : "=v"(d) : "v"(a), "v"(b));
    return d;
}
__device__ __forceinline__ v2f pk_fma(v2f a, v2f b, v2f c) {
    v2f d;
    asm("v_pk_fma_f32 %0, %1, %2, %3" : "=v"(d) : "v"(a), "v"(b), "v"(c));
    return d;
}

__global__ void __launch_bounds__(BLOCK)
nn_kernel(const float* __restrict__ preds,
          const float* __restrict__ targs,
          const float* __restrict__ subcoef,
          float* __restrict__ out) {
    __shared__ float4 sc4[NCHUNK * CH_F4];   // 18,432 B, padded chunks
    __shared__ float  wsum[BLOCK / 64];

    const int dir = blockIdx.z;          // 0: preds->targs (subcoef), 1: reverse
    const int b   = blockIdx.y;
    const int tid = threadIdx.x;

    const float* src = dir ? targs : preds;
    const float* dst = dir ? preds : targs;

    // Stage candidates pair-interleaved: slot i of chunk c holds
    // [x_{16c+2i}, x_{16c+2i+1}, y_{16c+2i}, y_{16c+2i+1}].
    const float* dstb = dst + (size_t)b * M * F;
    for (int g = tid; g < M / 2; g += BLOCK) {
        const float4 a = *reinterpret_cast<const float4*>(dstb + (size_t)(2 * g) * F);
        const float4 c = *reinterpret_cast<const float4*>(dstb + (size_t)(2 * g + 1) * F);
        sc4[(g >> 3) * CH_F4 + (g & 7)] = make_float4(a.x, c.x, a.y, c.y);
    }
    __syncthreads();

    // Each thread owns P query points (stride BLOCK for coalescing).
    const int base = blockIdx.x * (BLOCK * P);
    float px[P], py[P], p2s[P];
    v2f n2x[P], n2y[P], p2v[P];
    unsigned bkey[P];
    #pragma unroll
    for (int j = 0; j < P; ++j) {
        const int n = base + j * BLOCK + tid;
        const float2 p = *reinterpret_cast<const float2*>(src + ((size_t)b * N + n) * F);
        px[j] = p.x;  py[j] = p.y;
        p2s[j] = fmaf(p.y, p.y, p.x * p.x);
        const float ax = -2.0f * p.x, ay = -2.0f * p.y;
        n2x[j] = (v2f){ ax, ax };
        n2y[j] = (v2f){ ay, ay };
        p2v[j] = (v2f){ p2s[j], p2s[j] };
        bkey[j] = 0xFFFFFFFFu;
    }

    // Main scan: per chunk keep min VALUE only (v_min3_f32), fold packed key
    //   key = (bits(d2min) & 0xFFFFF800) | chunk_id   with v_min_u32.
    #pragma unroll 2
    for (int c = 0; c < NCHUNK; ++c) {
        const float4* chp = sc4 + c * CH_F4;
        float cb[P];
        #pragma unroll
        for (int j = 0; j < P; ++j) cb[j] = 3.4028235e38f;
        #pragma unroll
        for (int i = 0; i < CHUNK / 2; ++i) {
            const float4 q = chp[i];                  // uniform addr: broadcast
            const v2f XX = { q.x, q.y };
            const v2f YY = { q.z, q.w };
            const v2f NN = pk_fma(YY, YY, pk_mul(XX, XX));   // |t|^2 (packed)
            #pragma unroll
            for (int j = 0; j < P; ++j) {
                // d2 = |t|^2 + |p|^2 - 2 p.t  (>=0 up to rounding), 2-wide.
                v2f d = pk_fma(XX, n2x[j], pk_add(NN, p2v[j]));
                d = pk_fma(YY, n2y[j], d);
                cb[j] = min3f(d.x, d.y, cb[j]);
            }
        }
        #pragma unroll
        for (int j = 0; j < P; ++j) {
            const unsigned key = (fbits(cb[j]) & DMASK) | (unsigned)c;
            bkey[j] = key < bkey[j] ? key : bkey[j];
        }
    }

    // Tail: re-scan winning chunk (bit-identical scalar math) for the
    // first-occurrence index, then accumulate the L1 term.
    float c0 = 1.0f, c1 = 1.0f;
    if (dir == 0) { c0 = subcoef[0]; c1 = subcoef[1]; }
    float acc = 0.0f;
    #pragma unroll
    for (int j = 0; j < P; ++j) {
        const int cwin = (int)(bkey[j] & 0x7FFu);
        const unsigned dbits = bkey[j] & DMASK;
        const float a2x = -2.0f * px[j];
        const float a2y = -2.0f * py[j];
        const float4* chp = sc4 + cwin * CH_F4;      // divergent, bank-spread
        int iwin = 0x7FFFFFFF;
        #pragma unroll
        for (int i = 0; i < CHUNK / 2; ++i) {
            const float4 q = chp[i];
            // even candidate (q.x, q.z)
            float dA = fmaf(q.z, q.z, q.x * q.x);    // == NN half 0
            dA = fmaf(q.x, a2x, dA + p2s[j]);
            dA = fmaf(q.z, a2y, dA);
            const bool hA = (fbits(dA) & DMASK) == dbits;
            iwin = (hA && 2 * i < iwin) ? 2 * i : iwin;
            // odd candidate (q.y, q.w)
            float dB = fmaf(q.w, q.w, q.y * q.y);
            dB = fmaf(q.y, a2x, dB + p2s[j]);
            dB = fmaf(q.w, a2y, dB);
            const bool hB = (fbits(dB) & DMASK) == dbits;
            iwin = (hB && 2 * i + 1 < iwin) ? 2 * i + 1 : iwin;
        }
        if (iwin == 0x7FFFFFFF) iwin = 0;            // unreachable safety
        const float4 qq = chp[iwin >> 1];
        const float qx = (iwin & 1) ? qq.y : qq.x;
        const float qy = (iwin & 1) ? qq.w : qq.z;
        acc += fabsf(px[j] - qx) * c0 + fabsf(py[j] - qy) * c1;
    }

    // Wave (64) shuffle reduction -> block reduction -> one atomic per block.
    #pragma unroll
    for (int off = 32; off > 0; off >>= 1) acc += __shfl_down(acc, off, 64);
    if ((tid & 63) == 0) wsum[tid >> 6] = acc;
    __syncthreads();
    if (tid == 0) {
        float s = 0.0f;
        #pragma unroll
        for (int w = 0; w < BLOCK / 64; ++w) s += wsum[w];
        atomicAdd(out, s);
    }
}

extern "C" void kernel_launch(void* const* d_in, const int* in_sizes, int n_in,
                              void* d_out, int out_size, void* d_ws, size_t ws_size,
                              hipStream_t stream) {
    const float* preds   = (const float*)d_in[0];
    const float* targs   = (const float*)d_in[1];
    const float* subcoef = (const float*)d_in[2];
    float* out = (float*)d_out;

    hipMemsetAsync(out, 0, sizeof(float), stream);

    // 4 x 64 x 2 = 512 blocks -> 2 blocks/CU -> 8 waves/CU (2 per SIMD).
    dim3 grid(N / (BLOCK * P), B, 2);
    nn_kernel<<<grid, BLOCK, 0, stream>>>(preds, targs, subcoef, out);
}

// Round 8
// 114.913 us; speedup vs baseline: 1.4526x; 1.0849x over previous
//
#include <hip/hip_runtime.h>

// Bidirectional NN (Chamfer-style) L1 loss on 2-D points.
//   preds: (B=64, N=2048, F=4) fp32, targs: (B=64, M=2048, F=4) fp32,
//   subcoef: (D=2,) fp32. Distance over features [0:2) only.
//
// Round-7 structure: split-K over candidates + partial-key combine.
//  * nn_scan<S>: each block = (split s, batch b, dir) handles ALL 2048
//    queries (P=8/thread) x 2048/S candidates staged in LDS. Keyed distance
//      d'' = |t|^2 + 64 - 2 p.t   (= d2 - |p|^2 + 64 > 0: argmin-invariant,
//    bias 64 > max |p|^2 for N(0,1) inputs keeps it positive -> float bits
//    unsigned-monotone). |t|^2+64 amortized over 8 queries; inner loop =
//    2 v_pk_fma_f32 + v_min3_f32 per 2 candidates per query (~1.8 VALU/pc).
//    Per 16-candidate chunk fold key = (bits(min d'') & 0xFFFFFF80) | gchunk
//    (7-bit global chunk id, 128 chunks). Partial keys -> d_ws (no atomics).
//  * nn_combine: per query min over S partial keys, re-scan the winning
//    chunk from global with BIT-IDENTICAL scalar math, first masked match ==
//    first-occurrence argmin (same semantics as rounds 4-6: absmax 0.0),
//    L1 term, wave+block reduce, one atomicAdd. nn_scan zeroes *out
//    (stream order makes this safe) -> no memset node.
constexpr int B = 64;
constexpr int NQ = 2048;                 // queries per (dir,b)
constexpr int M = 2048;                  // candidates per (dir,b)
constexpr int F = 4;
constexpr int BLOCK = 256;
constexpr int P = 8;                     // queries per thread (BLOCK*P == NQ)
constexpr int CHUNK = 16;                // candidates per chunk
constexpr int NCHUNK = M / CHUNK;        // 128 global chunks (7 bits)
constexpr int CH_F4 = 9;                 // float4 slots per chunk (8 data + pad)
constexpr unsigned DMASK = 0xFFFFFF80u;  // low 7 bits carry chunk id
constexpr float BIAS = 64.0f;
constexpr int QTOT = 2 * B * NQ;         // 262144 query instances

typedef float v2f __attribute__((ext_vector_type(2)));

__device__ __forceinline__ unsigned fbits(float x) {
    union { float f; unsigned u; } c; c.f = x; return c.u;
}
__device__ __forceinline__ float min3f(float a, float b, float c) {
    float r;
    asm("v_min3_f32 %0, %1, %2, %3" : "=v"(r) : "v"(a), "v"(b), "v"(c));
    return r;
}
__device__ __forceinline__ v2f pk_mul(v2f a, v2f b) {
    v2f d; asm("v_pk_mul_f32 %0, %1, %2" : "=v"(d) : "v"(a), "v"(b)); return d;
}
__device__ __forceinline__ v2f pk_add(v2f a, v2f b) {
    v2f d; asm("v_pk_add_f32 %0, %1, %2" : "=v"(d) : "v"(a), "v"(b)); return d;
}
__device__ __forceinline__ v2f pk_fma(v2f a, v2f b, v2f c) {
    v2f d; asm("v_pk_fma_f32 %0, %1, %2, %3" : "=v"(d) : "v"(a), "v"(b), "v"(c)); return d;
}

// ---------------- scan: partial argmin keys over a candidate slice ----------
template <int S>
__global__ void __launch_bounds__(BLOCK)
nn_scan(const float* __restrict__ preds,
        const float* __restrict__ targs,
        unsigned* __restrict__ keys,
        float* __restrict__ out) {
    constexpr int CPB = NCHUNK / S;          // chunks per block
    __shared__ float4 sc4[CPB * CH_F4];

    const int s   = blockIdx.x;
    const int b   = blockIdx.y;
    const int dir = blockIdx.z;              // 0: preds->targs, 1: reverse
    const int tid = threadIdx.x;

    if (s == 0 && b == 0 && dir == 0 && tid == 0) *out = 0.0f;  // replaces memset

    const float* qsrc = dir ? targs : preds;
    const float* csrc = dir ? preds : targs;

    // Stage this block's candidate slice, pair-interleaved, padded chunks:
    // slot i of chunk c = [x_{2i}, x_{2i+1}, y_{2i}, y_{2i+1}].
    const float* cb_ = csrc + ((size_t)b * M + (size_t)s * CPB * CHUNK) * F;
    for (int g = tid; g < CPB * 8; g += BLOCK) {
        const float4 a = *reinterpret_cast<const float4*>(cb_ + (size_t)(2 * g) * F);
        const float4 c = *reinterpret_cast<const float4*>(cb_ + (size_t)(2 * g + 1) * F);
        sc4[(g >> 3) * CH_F4 + (g & 7)] = make_float4(a.x, c.x, a.y, c.y);
    }
    __syncthreads();

    // Each thread owns P=8 queries (stride BLOCK for coalescing).
    v2f n2x[P], n2y[P];
    unsigned bkey[P];
    #pragma unroll
    for (int j = 0; j < P; ++j) {
        const int n = j * BLOCK + tid;
        const float2 p = *reinterpret_cast<const float2*>(qsrc + ((size_t)b * NQ + n) * F);
        const float ax = -2.0f * p.x, ay = -2.0f * p.y;
        n2x[j] = (v2f){ ax, ax };
        n2y[j] = (v2f){ ay, ay };
        bkey[j] = 0xFFFFFFFFu;
    }
    const v2f biasv = (v2f){ BIAS, BIAS };

    for (int c = 0; c < CPB; ++c) {
        const float4* chp = sc4 + c * CH_F4;
        float cbm[P];
        #pragma unroll
        for (int j = 0; j < P; ++j) cbm[j] = 3.4028235e38f;
        #pragma unroll
        for (int i = 0; i < CHUNK / 2; ++i) {
            const float4 q = chp[i];                    // broadcast ds_read_b128
            const v2f XX = { q.x, q.y };
            const v2f YY = { q.z, q.w };
            // |t|^2 + 64, packed; amortized over all 8 queries.
            const v2f NN = pk_add(pk_fma(YY, YY, pk_mul(XX, XX)), biasv);
            #pragma unroll
            for (int j = 0; j < P; ++j) {
                v2f d = pk_fma(XX, n2x[j], NN);
                d = pk_fma(YY, n2y[j], d);
                cbm[j] = min3f(d.x, d.y, cbm[j]);
            }
        }
        const unsigned gc = (unsigned)(s * CPB + c);
        #pragma unroll
        for (int j = 0; j < P; ++j) {
            const unsigned key = (fbits(cbm[j]) & DMASK) | gc;
            bkey[j] = key < bkey[j] ? key : bkey[j];
        }
    }

    // Store partial keys (coalesced).
    unsigned* kout = keys + (size_t)s * QTOT + ((size_t)dir * B + b) * NQ;
    #pragma unroll
    for (int j = 0; j < P; ++j) kout[j * BLOCK + tid] = bkey[j];
}

// ---------------- combine: merge splits, recover index, L1, reduce ----------
__global__ void __launch_bounds__(BLOCK)
nn_combine(const float* __restrict__ preds,
           const float* __restrict__ targs,
           const float* __restrict__ subcoef,
           const unsigned* __restrict__ keys, int nsplit,
           float* __restrict__ out) {
    __shared__ float wsum[BLOCK / 64];
    const int qid = blockIdx.x * BLOCK + threadIdx.x;   // 0 .. QTOT-1
    const int dir = qid >> 17;                          // QTOT/2 = 2^17
    const int b   = (qid >> 11) & 63;
    const int n   = qid & 2047;

    unsigned k = 0xFFFFFFFFu;
    for (int s = 0; s < nsplit; ++s) {
        const unsigned ks = keys[(size_t)s * QTOT + qid];
        k = ks < k ? ks : k;
    }
    const int cwin = (int)(k & 0x7Fu);
    const unsigned dbits = k & DMASK;

    const float* qsrc = dir ? targs : preds;
    const float* csrc = dir ? preds : targs;
    const float2 p = *reinterpret_cast<const float2*>(qsrc + ((size_t)b * NQ + n) * F);
    const float ax = -2.0f * p.x, ay = -2.0f * p.y;

    // Re-scan winning chunk from global with BIT-IDENTICAL arithmetic
    // (packed halves are IEEE-identical to scalar): first masked match.
    const float4* cand = reinterpret_cast<const float4*>(
        csrc + ((size_t)b * M + (size_t)cwin * CHUNK) * F);
    float qx = 0.0f, qy = 0.0f;
    int found = 0;
    #pragma unroll 4
    for (int i = 0; i < CHUNK; ++i) {
        const float4 t4 = cand[i];
        const float x = t4.x, y = t4.y;
        float d = fmaf(y, y, x * x) + BIAS;   // mul, fma, add: matches pk chain
        d = fmaf(x, ax, d);
        d = fmaf(y, ay, d);
        const bool hit = (((fbits(d) & DMASK) == dbits) && !found);
        qx = hit ? x : qx;
        qy = hit ? y : qy;
        found = hit ? 1 : found;
    }
    if (!found) { qx = cand[0].x; qy = cand[0].y; }     // unreachable safety

    float c0 = 1.0f, c1 = 1.0f;
    if (dir == 0) { c0 = subcoef[0]; c1 = subcoef[1]; }
    float acc = fabsf(p.x - qx) * c0 + fabsf(p.y - qy) * c1;

    #pragma unroll
    for (int off = 32; off > 0; off >>= 1) acc += __shfl_down(acc, off, 64);
    if ((threadIdx.x & 63) == 0) wsum[threadIdx.x >> 6] = acc;
    __syncthreads();
    if (threadIdx.x == 0) {
        float ssum = 0.0f;
        #pragma unroll
        for (int w = 0; w < BLOCK / 64; ++w) ssum += wsum[w];
        atomicAdd(out, ssum);
    }
}

// ---------------- fallback (ws too small): round-6 kernel ----------------
constexpr int PF = 2;
__global__ void __launch_bounds__(BLOCK)
nn_fallback(const float* __restrict__ preds,
            const float* __restrict__ targs,
            const float* __restrict__ subcoef,
            float* __restrict__ out) {
    __shared__ float4 sc4[NCHUNK * CH_F4];
    __shared__ float  wsum[BLOCK / 64];
    const int dir = blockIdx.z, b = blockIdx.y, tid = threadIdx.x;
    const float* src = dir ? targs : preds;
    const float* dst = dir ? preds : targs;
    const float* dstb = dst + (size_t)b * M * F;
    for (int g = tid; g < M / 2; g += BLOCK) {
        const float4 a = *reinterpret_cast<const float4*>(dstb + (size_t)(2 * g) * F);
        const float4 c = *reinterpret_cast<const float4*>(dstb + (size_t)(2 * g + 1) * F);
        sc4[(g >> 3) * CH_F4 + (g & 7)] = make_float4(a.x, c.x, a.y, c.y);
    }
    __syncthreads();
    const int base = blockIdx.x * (BLOCK * PF);
    float px[PF], py[PF];
    v2f n2x[PF], n2y[PF];
    unsigned bkey[PF];
    #pragma unroll
    for (int j = 0; j < PF; ++j) {
        const int n = base + j * BLOCK + tid;
        const float2 p = *reinterpret_cast<const float2*>(src + ((size_t)b * NQ + n) * F);
        px[j] = p.x; py[j] = p.y;
        n2x[j] = (v2f){ -2.0f * p.x, -2.0f * p.x };
        n2y[j] = (v2f){ -2.0f * p.y, -2.0f * p.y };
        bkey[j] = 0xFFFFFFFFu;
    }
    const v2f biasv = (v2f){ BIAS, BIAS };
    for (int c = 0; c < NCHUNK; ++c) {
        const float4* chp = sc4 + c * CH_F4;
        float cbm[PF];
        #pragma unroll
        for (int j = 0; j < PF; ++j) cbm[j] = 3.4028235e38f;
        #pragma unroll
        for (int i = 0; i < CHUNK / 2; ++i) {
            const float4 q = chp[i];
            const v2f XX = { q.x, q.y };
            const v2f YY = { q.z, q.w };
            const v2f NN = pk_add(pk_fma(YY, YY, pk_mul(XX, XX)), biasv);
            #pragma unroll
            for (int j = 0; j < PF; ++j) {
                v2f d = pk_fma(XX, n2x[j], NN);
                d = pk_fma(YY, n2y[j], d);
                cbm[j] = min3f(d.x, d.y, cbm[j]);
            }
        }
        #pragma unroll
        for (int j = 0; j < PF; ++j) {
            const unsigned key = (fbits(cbm[j]) & DMASK) | (unsigned)c;
            bkey[j] = key < bkey[j] ? key : bkey[j];
        }
    }
    float c0 = 1.0f, c1 = 1.0f;
    if (dir == 0) { c0 = subcoef[0]; c1 = subcoef[1]; }
    float acc = 0.0f;
    #pragma unroll
    for (int j = 0; j < PF; ++j) {
        const int cwin = (int)(bkey[j] & 0x7Fu);
        const unsigned dbits = bkey[j] & DMASK;
        const float a2x = -2.0f * px[j], a2y = -2.0f * py[j];
        const float4* chp = sc4 + cwin * CH_F4;
        float qx = 0.0f, qy = 0.0f; int found = 0;
        #pragma unroll
        for (int i = 0; i < CHUNK / 2; ++i) {
            const float4 q = chp[i];
            float dA = fmaf(q.z, q.z, q.x * q.x) + BIAS;
            dA = fmaf(q.x, a2x, dA); dA = fmaf(q.z, a2y, dA);
            bool hit = (((fbits(dA) & DMASK) == dbits) && !found);
            qx = hit ? q.x : qx; qy = hit ? q.z : qy; found = hit ? 1 : found;
            float dB = fmaf(q.w, q.w, q.y * q.y) + BIAS;
            dB = fmaf(q.y, a2x, dB); dB = fmaf(q.w, a2y, dB);
            hit = (((fbits(dB) & DMASK) == dbits) && !found);
            qx = hit ? q.y : qx; qy = hit ? q.w : qy; found = hit ? 1 : found;
        }
        acc += fabsf(px[j] - qx) * c0 + fabsf(py[j] - qy) * c1;
    }
    #pragma unroll
    for (int off = 32; off > 0; off >>= 1) acc += __shfl_down(acc, off, 64);
    if ((tid & 63) == 0) wsum[tid >> 6] = acc;
    __syncthreads();
    if (tid == 0) {
        float ssum = 0.0f;
        #pragma unroll
        for (int w = 0; w < BLOCK / 64; ++w) ssum += wsum[w];
        atomicAdd(out, ssum);
    }
}

extern "C" void kernel_launch(void* const* d_in, const int* in_sizes, int n_in,
                              void* d_out, int out_size, void* d_ws, size_t ws_size,
                              hipStream_t stream) {
    const float* preds   = (const float*)d_in[0];
    const float* targs   = (const float*)d_in[1];
    const float* subcoef = (const float*)d_in[2];
    float* out = (float*)d_out;

    const size_t need8 = (size_t)8 * QTOT * sizeof(unsigned);  // 8 MB
    const size_t need4 = (size_t)4 * QTOT * sizeof(unsigned);
    const size_t need2 = (size_t)2 * QTOT * sizeof(unsigned);

    if (d_ws != nullptr && ws_size >= need2) {
        unsigned* keys = (unsigned*)d_ws;
        int S;
        if (ws_size >= need8)      { S = 8; nn_scan<8><<<dim3(8, B, 2), BLOCK, 0, stream>>>(preds, targs, keys, out); }
        else if (ws_size >= need4) { S = 4; nn_scan<4><<<dim3(4, B, 2), BLOCK, 0, stream>>>(preds, targs, keys, out); }
        else                       { S = 2; nn_scan<2><<<dim3(2, B, 2), BLOCK, 0, stream>>>(preds, targs, keys, out); }
        nn_combine<<<dim3(QTOT / BLOCK), BLOCK, 0, stream>>>(
            preds, targs, subcoef, keys, S, out);
    } else {
        hipMemsetAsync(out, 0, sizeof(float), stream);
        dim3 grid(NQ / (BLOCK * PF), B, 2);
        nn_fallback<<<grid, BLOCK, 0, stream>>>(preds, targs, subcoef, out);
    }
}